// Round 10
// baseline (198.503 us; speedup 1.0000x reference)
//
#include <hip/hip_runtime.h>
#include <hip/hip_bf16.h>
#include <cstdint>

// ---------------------------------------------------------------------------
// SAGENet (2-layer SAGEConv 'pool').
// R10: no agg zero-init (boundary atomicMax is poison-safe for values >= 0;
// empty-dst rows masked at GEMM A-staging via cnt arrays); leaner prep grids.
// 8 dispatches:
//   K1 pack weights + zero cnt/done; K2 count; K3 chunk-scan; K4 fill
//   D5 pool0_fused: agg0 = segmax(relu(h_item[srcs0]@Wpool0+b))   [R6-verified]
//   D6 gemm3: h = relu(h_item@Wself0 + agg0@Wneigh0 + bias0)      [N1,256] bf16
//   D7 pool1_fused: agg1 = segmax(relu(h[srcs1]@Wpool1+b))        [R7-verified]
//   D8 gemm6: out = h_item_dst + h@Wself1 + agg1@Wneigh1 + bias1  [N2,128]
// Segment-max: dst-sorted edges; interior segments plain full-row stores,
// block-boundary segments int-punned fp32 atomicMax (values >= 0; poison
// 0xAAAAAAAA is negative as int -> max always replaces; replay values are
// idempotent under max with identical inputs).
// Shapes fixed: F=128, N1=40960, N2=4096, E0=409600, E1=40960 (%256==0).
// ---------------------------------------------------------------------------

typedef unsigned int uint32;
typedef unsigned short ushort_t;

typedef __attribute__((ext_vector_type(8))) short short8v;   // 8 bf16 (4 VGPR)
typedef __attribute__((ext_vector_type(4))) float float4v;   // MFMA acc

__device__ __forceinline__ float bf_to_f(unsigned short u) {
    union { uint32 u; float f; } cv; cv.u = ((uint32)u) << 16; return cv.f;
}
__device__ __forceinline__ unsigned short f_to_bf(float f) {
    union { float f; uint32 u; } cv; cv.f = f;
    uint32 u = cv.u;
    uint32 r = (u + 0x7FFFu + ((u >> 16) & 1u)) >> 16;  // RNE
    return (unsigned short)r;
}

__device__ __forceinline__ int wave_incl_scan(int v) {
    #pragma unroll
    for (int s = 1; s < 64; s <<= 1) {
        int t = __shfl_up(v, s, 64);
        if ((int)(threadIdx.x & 63) >= s) v += t;
    }
    return v;
}

// ---------------- MFMA GEMM ------------------------------------------------
// mask (optional, fp32 path only): rows with mask[row]==0 stage zeros
// (agg rows of empty segments are never written -> garbage; reference
// semantics say they contribute 0).
template<int KT, bool ABF>
__device__ __forceinline__ void gemm_seg(
    const void* __restrict__ Av, const ushort_t* __restrict__ Wp, int N,
    const int* __restrict__ mask,
    int row0, int col0, int tid, int wr, int wc, int l15, int g,
    ushort_t* lds, float4v (&acc)[4][4])
{
    constexpr int ldl = KT + 8;
    __syncthreads();
    if constexpr (ABF) {
        const ushort_t* A = (const ushort_t*)Av;
        constexpr int C8 = KT / 8;
        constexpr int TOT = 128 * C8;
        #pragma unroll 4
        for (int L = tid; L < TOT; L += 256) {
            int row = L / C8;
            int c8  = (L % C8) * 8;
            *(uint4*)&lds[row * ldl + c8] =
                *(const uint4*)(A + (size_t)(row0 + row) * KT + c8);
        }
    } else {
        const float* A = (const float*)Av;
        constexpr int C4 = KT / 4;
        constexpr int TOT = 128 * C4;
        #pragma unroll 4
        for (int L = tid; L < TOT; L += 256) {
            int row = L / C4;
            int c4  = (L % C4) * 4;
            float4 v = *(const float4*)(A + (size_t)(row0 + row) * KT + c4);
            if (mask && mask[row0 + row] == 0) v = make_float4(0.f, 0.f, 0.f, 0.f);
            ushort4 pk = make_ushort4(f_to_bf(v.x), f_to_bf(v.y), f_to_bf(v.z), f_to_bf(v.w));
            *(ushort4*)&lds[row * ldl + c4] = pk;
        }
    }
    __syncthreads();

    #pragma unroll
    for (int s = 0; s < KT / 32; ++s) {
        const int kb = s * 4 + g;
        short8v bfr[4], afr[4];
        #pragma unroll
        for (int ni = 0; ni < 4; ++ni) {
            int col = col0 + wc * 64 + ni * 16 + l15;
            bfr[ni] = *(const short8v*)(Wp + ((size_t)kb * N + col) * 8);
        }
        #pragma unroll
        for (int mi = 0; mi < 4; ++mi) {
            int row = wr * 64 + mi * 16 + l15;
            afr[mi] = *(const short8v*)&lds[row * ldl + s * 32 + g * 8];
        }
        #pragma unroll
        for (int mi = 0; mi < 4; ++mi)
            #pragma unroll
            for (int ni = 0; ni < 4; ++ni)
                acc[mi][ni] = __builtin_amdgcn_mfma_f32_16x16x32_bf16(
                    afr[mi], bfr[ni], acc[mi][ni], 0, 0, 0);
    }
}

template<bool RELU, bool BF16_OUT, bool HAS_ADD, int K0T, int K1T, bool A0BF, bool A1BF, int MINW>
__global__ __launch_bounds__(256, MINW) void gemm_mfma(
    const void* __restrict__ A0, const ushort_t* __restrict__ Wp0,
    const void* __restrict__ A1, const ushort_t* __restrict__ Wp1,
    const int* __restrict__ mask1,
    const float* __restrict__ bias, const float* __restrict__ addsrc,
    void* __restrict__ Cout, int N)
{
    extern __shared__ ushort_t lds[];
    const int tid  = threadIdx.x;
    const int lane = tid & 63;
    const int wid  = tid >> 6;
    const int wr = wid >> 1, wc = wid & 1;
    const int row0 = blockIdx.x * 128;
    const int col0 = blockIdx.y * 128;
    const int l15 = lane & 15, g = lane >> 4;

    float4v acc[4][4];
    #pragma unroll
    for (int i = 0; i < 4; ++i)
        #pragma unroll
        for (int j = 0; j < 4; ++j)
            acc[i][j] = (float4v){0.f, 0.f, 0.f, 0.f};

    gemm_seg<K0T, A0BF>(A0, Wp0, N, nullptr, row0, col0, tid, wr, wc, l15, g, lds, acc);
    if constexpr (K1T > 0)
        gemm_seg<K1T, A1BF>(A1, Wp1, N, mask1, row0, col0, tid, wr, wc, l15, g, lds, acc);

    // epilogue: C/D layout col=lane&15, row=(lane>>4)*4+reg  [m89-verified]
    if constexpr (BF16_OUT) {
        __syncthreads();
        #pragma unroll
        for (int mi = 0; mi < 4; ++mi) {
            #pragma unroll
            for (int ni = 0; ni < 4; ++ni) {
                const int rowl = wr * 64 + mi * 16 + g * 4;
                const int coll = wc * 64 + ni * 16 + l15;
                const float bs = bias[col0 + coll];
                #pragma unroll
                for (int q = 0; q < 4; ++q) {
                    float v = acc[mi][ni][q] + bs;
                    if (RELU) v = fmaxf(v, 0.f);
                    lds[(rowl + q) * 136 + coll] = f_to_bf(v);
                }
            }
        }
        __syncthreads();
        ushort_t* Cb = (ushort_t*)Cout;
        const int rloc = tid >> 4, c8 = (tid & 15) * 8;
        #pragma unroll
        for (int p = 0; p < 8; ++p) {
            int r = p * 16 + rloc;
            uint4 v = *(const uint4*)&lds[r * 136 + c8];
            *(uint4*)&Cb[(size_t)(row0 + r) * N + col0 + c8] = v;
        }
    } else {
        float* C = (float*)Cout;
        #pragma unroll
        for (int mi = 0; mi < 4; ++mi) {
            #pragma unroll
            for (int ni = 0; ni < 4; ++ni) {
                const int rowb = row0 + wr * 64 + mi * 16 + g * 4;
                const int col  = col0 + wc * 64 + ni * 16 + l15;
                const float bs = bias[col];
                #pragma unroll
                for (int q = 0; q < 4; ++q) {
                    float v = acc[mi][ni][q] + bs;
                    if (HAS_ADD) v += addsrc[(size_t)(rowb + q) * N + col];
                    if (RELU) v = fmaxf(v, 0.f);
                    C[(size_t)(rowb + q) * N + col] = v;
                }
            }
        }
    }
}

// ---------------- fused pool GEMM + segment-max ----------------------------
__global__ __launch_bounds__(256, 4) void pool0_fused(
    const float* __restrict__ hsrc, const ushort_t* __restrict__ Wp,
    const float* __restrict__ bias,
    const int* __restrict__ srcs, const int* __restrict__ dsts,
    int* __restrict__ agg, int E)
{
    constexpr int KT = 128, ldl = KT + 8;      // 136
    extern __shared__ ushort_t lds[];
    __shared__ int sIdx[128], sd[128];
    __shared__ int segbeg[129];
    __shared__ int wps[4];
    __shared__ int s_first_start, s_last_end;

    const int tid  = threadIdx.x;
    const int lane = tid & 63;
    const int wid  = tid >> 6;
    const int wr = wid >> 1, wc = wid & 1;
    const int l15 = lane & 15, g = lane >> 4;
    const int r0 = blockIdx.x * 128;

    if (tid < 128) { sIdx[tid] = srcs[r0 + tid]; sd[tid] = dsts[r0 + tid]; }
    __syncthreads();

    #pragma unroll 4
    for (int L = tid; L < 128 * 32; L += 256) {
        int row = L >> 5;
        int c4  = (L & 31) * 4;
        float4 v = *(const float4*)(hsrc + (size_t)sIdx[row] * KT + c4);
        ushort4 pk = make_ushort4(f_to_bf(v.x), f_to_bf(v.y), f_to_bf(v.z), f_to_bf(v.w));
        *(ushort4*)&lds[row * ldl + c4] = pk;
    }
    __syncthreads();

    float4v acc[4][4];
    #pragma unroll
    for (int i = 0; i < 4; ++i)
        #pragma unroll
        for (int j = 0; j < 4; ++j)
            acc[i][j] = (float4v){0.f, 0.f, 0.f, 0.f};

    #pragma unroll
    for (int s = 0; s < KT / 32; ++s) {
        const int kb = s * 4 + g;
        short8v bfr[4], afr[4];
        #pragma unroll
        for (int ni = 0; ni < 4; ++ni) {
            int col = wc * 64 + ni * 16 + l15;
            bfr[ni] = *(const short8v*)(Wp + ((size_t)kb * 128 + col) * 8);
        }
        #pragma unroll
        for (int mi = 0; mi < 4; ++mi) {
            int row = wr * 64 + mi * 16 + l15;
            afr[mi] = *(const short8v*)&lds[row * ldl + s * 32 + g * 8];
        }
        #pragma unroll
        for (int mi = 0; mi < 4; ++mi)
            #pragma unroll
            for (int ni = 0; ni < 4; ++ni)
                acc[mi][ni] = __builtin_amdgcn_mfma_f32_16x16x32_bf16(
                    afr[mi], bfr[ni], acc[mi][ni], 0, 0, 0);
    }

    __syncthreads();
    #pragma unroll
    for (int mi = 0; mi < 4; ++mi) {
        #pragma unroll
        for (int ni = 0; ni < 4; ++ni) {
            const int rowl = wr * 64 + mi * 16 + g * 4;
            const int coll = wc * 64 + ni * 16 + l15;
            const float bs = bias[coll];
            #pragma unroll
            for (int q = 0; q < 4; ++q) {
                float v = fmaxf(acc[mi][ni][q] + bs, 0.f);
                lds[(rowl + q) * ldl + coll] = f_to_bf(v);
            }
        }
    }

    int flag = 0;
    if (tid < 128) flag = (tid == 0) || (sd[tid] != sd[tid - 1]);
    int isc = wave_incl_scan(flag);
    if (lane == 63) wps[wid] = isc;
    if (tid == 0) {
        s_first_start = (r0 == 0) || (dsts[r0 - 1] != sd[0]);
        s_last_end    = (r0 + 128 == E) || (dsts[r0 + 128] != sd[127]);
    }
    __syncthreads();
    int woff = (wid >= 1) ? wps[0] : 0;
    if (tid < 128 && flag) segbeg[woff + isc - 1] = tid;
    __syncthreads();
    const int nseg = wps[0] + wps[1];
    const bool first_start = s_first_start, last_end = s_last_end;

    for (int it = tid; it < nseg * 64; it += 256) {
        int s  = it >> 6;
        int cp = it & 63;
        int beg = segbeg[s];
        int end = (s + 1 < nseg) ? segbeg[s + 1] : 128;
        int d = sd[beg];
        uint32 mx0 = 0, mx1 = 0;
        for (int r = beg; r < end; ++r) {
            ushort2 v = *(const ushort2*)&lds[r * ldl + cp * 2];
            if (v.x > mx0) mx0 = v.x;
            if (v.y > mx1) mx1 = v.y;
        }
        float f0 = bf_to_f((ushort_t)mx0), f1 = bf_to_f((ushort_t)mx1);
        int* p = agg + (size_t)d * 128 + cp * 2;
        bool interior = (s > 0 || first_start) && (s < nseg - 1 || last_end);
        if (interior) {
            *(float2*)p = make_float2(f0, f1);
        } else {
            atomicMax(p,     __float_as_int(f0));
            atomicMax(p + 1, __float_as_int(f1));
        }
    }
}

// layer-1 variant: K=256, A gathered from bf16 h; 128-col half per blockIdx.y.
__global__ __launch_bounds__(256, 2) void pool1_fused(
    const ushort_t* __restrict__ hsrc,      // bf16 [N1,256]
    const ushort_t* __restrict__ Wp,        // packed [256/8][256][8]
    const float* __restrict__ bias,         // [256]
    const int* __restrict__ srcs, const int* __restrict__ dsts,
    int* __restrict__ agg, int E)           // fp32 [N2,256]
{
    constexpr int KT = 256, ldl = KT + 8;   // 264
    constexpr int ldt = 136;
    extern __shared__ ushort_t lds[];
    __shared__ int sIdx[128], sd[128];
    __shared__ int segbeg[129];
    __shared__ int wps[4];
    __shared__ int s_first_start, s_last_end;

    const int tid  = threadIdx.x;
    const int lane = tid & 63;
    const int wid  = tid >> 6;
    const int wr = wid >> 1, wc = wid & 1;
    const int l15 = lane & 15, g = lane >> 4;
    const int r0 = blockIdx.x * 128;
    const int col0 = blockIdx.y * 128;

    if (tid < 128) { sIdx[tid] = srcs[r0 + tid]; sd[tid] = dsts[r0 + tid]; }
    __syncthreads();

    #pragma unroll 4
    for (int L = tid; L < 128 * 32; L += 256) {
        int row = L >> 5;
        int c8  = (L & 31) * 8;
        *(uint4*)&lds[row * ldl + c8] =
            *(const uint4*)(hsrc + (size_t)sIdx[row] * KT + c8);
    }
    __syncthreads();

    float4v acc[4][4];
    #pragma unroll
    for (int i = 0; i < 4; ++i)
        #pragma unroll
        for (int j = 0; j < 4; ++j)
            acc[i][j] = (float4v){0.f, 0.f, 0.f, 0.f};

    #pragma unroll
    for (int s = 0; s < KT / 32; ++s) {
        const int kb = s * 4 + g;
        short8v bfr[4], afr[4];
        #pragma unroll
        for (int ni = 0; ni < 4; ++ni) {
            int col = col0 + wc * 64 + ni * 16 + l15;
            bfr[ni] = *(const short8v*)(Wp + ((size_t)kb * 256 + col) * 8);
        }
        #pragma unroll
        for (int mi = 0; mi < 4; ++mi) {
            int row = wr * 64 + mi * 16 + l15;
            afr[mi] = *(const short8v*)&lds[row * ldl + s * 32 + g * 8];
        }
        #pragma unroll
        for (int mi = 0; mi < 4; ++mi)
            #pragma unroll
            for (int ni = 0; ni < 4; ++ni)
                acc[mi][ni] = __builtin_amdgcn_mfma_f32_16x16x32_bf16(
                    afr[mi], bfr[ni], acc[mi][ni], 0, 0, 0);
    }

    __syncthreads();
    #pragma unroll
    for (int mi = 0; mi < 4; ++mi) {
        #pragma unroll
        for (int ni = 0; ni < 4; ++ni) {
            const int rowl = wr * 64 + mi * 16 + g * 4;
            const int coll = wc * 64 + ni * 16 + l15;
            const float bs = bias[col0 + coll];
            #pragma unroll
            for (int q = 0; q < 4; ++q) {
                float v = fmaxf(acc[mi][ni][q] + bs, 0.f);
                lds[(rowl + q) * ldt + coll] = f_to_bf(v);
            }
        }
    }

    int flag = 0;
    if (tid < 128) flag = (tid == 0) || (sd[tid] != sd[tid - 1]);
    int isc = wave_incl_scan(flag);
    if (lane == 63) wps[wid] = isc;
    if (tid == 0) {
        s_first_start = (r0 == 0) || (dsts[r0 - 1] != sd[0]);
        s_last_end    = (r0 + 128 == E) || (dsts[r0 + 128] != sd[127]);
    }
    __syncthreads();
    int woff = (wid >= 1) ? wps[0] : 0;
    if (tid < 128 && flag) segbeg[woff + isc - 1] = tid;
    __syncthreads();
    const int nseg = wps[0] + wps[1];
    const bool first_start = s_first_start, last_end = s_last_end;

    for (int it = tid; it < nseg * 64; it += 256) {
        int s  = it >> 6;
        int cp = it & 63;
        int beg = segbeg[s];
        int end = (s + 1 < nseg) ? segbeg[s + 1] : 128;
        int d = sd[beg];
        uint32 mx0 = 0, mx1 = 0;
        for (int r = beg; r < end; ++r) {
            ushort2 v = *(const ushort2*)&lds[r * ldt + cp * 2];
            if (v.x > mx0) mx0 = v.x;
            if (v.y > mx1) mx1 = v.y;
        }
        float f0 = bf_to_f((ushort_t)mx0), f1 = bf_to_f((ushort_t)mx1);
        int* p = agg + (size_t)d * 256 + col0 + cp * 2;
        bool interior = (s > 0 || first_start) && (s < nseg - 1 || last_end);
        if (interior) {
            *(float2*)p = make_float2(f0, f1);
        } else {
            atomicMax(p,     __float_as_int(f0));
            atomicMax(p + 1, __float_as_int(f1));
        }
    }
}

// ---------------- prep kernels ---------------------------------------------
struct PSeg { const float* src; ushort_t* dst; int lgN; int N; int base; };

struct PrepArgs {
    PSeg s0, s1, s2, s3, s4, s5; int wtotal;
    const int *edst0, *esrc0; int E0;
    const int *edst1, *esrc1; int E1;
    int *cnt0, *cur0, *srcs0, *dsts0; int n0;
    int *cnt1, *cur1, *srcs1, *dsts1; int n1;
    int *part0, *base0;                 // [n0/256]
    int *part1, *base1;                 // [n1/256]
    int *done;
};

__device__ __forceinline__ void pack_one(const PrepArgs& a, int idx)
{
    PSeg s;
    if      (idx >= a.s5.base) s = a.s5;
    else if (idx >= a.s4.base) s = a.s4;
    else if (idx >= a.s3.base) s = a.s3;
    else if (idx >= a.s2.base) s = a.s2;
    else if (idx >= a.s1.base) s = a.s1;
    else                       s = a.s0;
    int e = idx - s.base;
    int k = e >> s.lgN;
    int n = e & (s.N - 1);
    s.dst[((size_t)(k >> 3) * s.N + n) * 8 + (k & 7)] = f_to_bf(s.src[e]);
}

// K1: pack weights + zero cnt0/cnt1/done (no agg zeroing needed).
__global__ __launch_bounds__(256) void prep_pack(PrepArgs a)
{
    const int gid = blockIdx.x * 256 + threadIdx.x;
    const int nth = gridDim.x * 256;
    if (gid == 0) *a.done = 0;
    for (int i = gid; i < a.n0; i += nth) a.cnt0[i] = 0;
    for (int i = gid; i < a.n1; i += nth) a.cnt1[i] = 0;
    for (int i = gid; i < a.wtotal; i += nth) pack_one(a, i);
}

// K2: count (grid-stride over both layers' edges).
__global__ __launch_bounds__(256) void prep_count(PrepArgs a)
{
    const int gid = blockIdx.x * 256 + threadIdx.x;
    const int nth = gridDim.x * 256;
    const int T = a.E0 + a.E1;
    for (int i = gid; i < T; i += nth) {
        if (i < a.E0) atomicAdd(&a.cnt0[a.edst0[i]], 1);
        else          atomicAdd(&a.cnt1[a.edst1[i - a.E0]], 1);
    }
}

// K3: per-256-chunk exclusive scan -> cur (within-chunk offsets) + partial.
// Last-finishing block scans the 176 partials -> base arrays.
__global__ __launch_bounds__(256) void prep_scan(PrepArgs a)
{
    __shared__ int wsum[4];
    __shared__ int s_last;
    const int tid = threadIdx.x;
    const int lane = tid & 63, wid = tid >> 6;
    const int nchunk0 = a.n0 >> 8;          // 160
    const int nchunk1 = a.n1 >> 8;          // 16
    const int c = blockIdx.x;
    const bool is0 = (c < nchunk0);
    const int cc = is0 ? c : (c - nchunk0);
    int* cnt  = is0 ? a.cnt0  : a.cnt1;
    int* cur  = is0 ? a.cur0  : a.cur1;
    int* part = is0 ? a.part0 : a.part1;
    const int base = cc * 256;

    int v = cnt[base + tid];
    int is = wave_incl_scan(v);
    if (lane == 63) wsum[wid] = is;
    __syncthreads();
    if (tid == 0) {
        int acc = 0;
        #pragma unroll
        for (int j = 0; j < 4; ++j) { int t = wsum[j]; wsum[j] = acc; acc += t; }
    }
    __syncthreads();
    cur[base + tid] = wsum[wid] + is - v;
    if (tid == 255) part[cc] = wsum[3] + is;   // chunk total

    __syncthreads();
    if (tid == 0) {
        __threadfence();
        s_last = (atomicAdd(a.done, 1) == (int)gridDim.x - 1);
    }
    __syncthreads();
    if (s_last) {
        __threadfence();
        int p0 = (tid < nchunk0) ? a.part0[tid] : 0;
        int isc = wave_incl_scan(p0);
        __syncthreads();
        if (lane == 63) wsum[wid] = isc;
        __syncthreads();
        if (tid == 0) {
            int acc = 0;
            #pragma unroll
            for (int j = 0; j < 4; ++j) { int t = wsum[j]; wsum[j] = acc; acc += t; }
        }
        __syncthreads();
        if (tid < nchunk0) a.base0[tid] = wsum[wid] + isc - p0;
        if (tid == 0) {
            int acc = 0;
            for (int j = 0; j < nchunk1; ++j) { a.base1[j] = acc; acc += a.part1[j]; }
        }
    }
}

// K4: fill dst-sorted srcs/dsts: pos = base[d>>8] + atomicAdd(cur[d]).
__global__ __launch_bounds__(256) void prep_fill(PrepArgs a)
{
    const int gid = blockIdx.x * 256 + threadIdx.x;
    const int nth = gridDim.x * 256;
    const int T = a.E0 + a.E1;
    for (int i = gid; i < T; i += nth) {
        if (i < a.E0) {
            int d = a.edst0[i];
            int p = a.base0[d >> 8] + atomicAdd(&a.cur0[d], 1);
            a.srcs0[p] = a.esrc0[i];
            a.dsts0[p] = d;
        } else {
            int d = a.edst1[i - a.E0];
            int p = a.base1[d >> 8] + atomicAdd(&a.cur1[d], 1);
            a.srcs1[p] = a.esrc1[i - a.E0];
            a.dsts1[p] = d;
        }
    }
}

// ---------------------------------------------------------------------------

extern "C" void kernel_launch(void* const* d_in, const int* in_sizes, int n_in,
                              void* d_out, int out_size, void* d_ws, size_t ws_size,
                              hipStream_t stream)
{
    const float* h_item     = (const float*)d_in[0];
    const float* h_item_dst = (const float*)d_in[1];
    const int*   esrc0      = (const int*)d_in[2];
    const int*   edst0      = (const int*)d_in[3];
    const int*   esrc1      = (const int*)d_in[4];
    const int*   edst1      = (const int*)d_in[5];
    const float* W_pool0  = (const float*)d_in[7];
    const float* b_pool0  = (const float*)d_in[8];
    const float* W_self0  = (const float*)d_in[9];
    const float* W_neigh0 = (const float*)d_in[10];
    const float* bias0    = (const float*)d_in[11];
    const float* W_pool1  = (const float*)d_in[12];
    const float* b_pool1  = (const float*)d_in[13];
    const float* W_self1  = (const float*)d_in[14];
    const float* W_neigh1 = (const float*)d_in[15];
    const float* bias1    = (const float*)d_in[16];

    const int F  = 128;
    const int N2 = in_sizes[1] / F;     // 4096
    const int E0 = in_sizes[2];         // 409600 (%256==0)
    const int E1 = in_sizes[4];         // 40960  (%256==0)
    const int N1 = 40960;               // num_mid (fixed)

    auto aup = [](size_t x) { return (x + 255) & ~(size_t)255; };
    char* p = (char*)d_ws;

    float* agg0 = (float*)p;        p += aup((size_t)N1 * F * 4);        // fp32 [N1,128]
    ushort_t* h = (ushort_t*)p;     p += aup((size_t)N1 * 2 * F * 2);    // bf16 [N1,256]
    float* agg1 = (float*)p;        p += aup((size_t)N2 * 2 * F * 4);    // fp32 [N2,256]
    int* cnt0  = (int*)p;           p += aup((size_t)N1 * 4);
    int* cur0  = (int*)p;           p += aup((size_t)N1 * 4);
    int* srcs0 = (int*)p;           p += aup((size_t)E0 * 4);
    int* dsts0 = (int*)p;           p += aup((size_t)E0 * 4);
    int* cnt1  = (int*)p;           p += aup((size_t)N2 * 4);
    int* cur1  = (int*)p;           p += aup((size_t)N2 * 4);
    int* srcs1 = (int*)p;           p += aup((size_t)E1 * 4);
    int* dsts1 = (int*)p;           p += aup((size_t)E1 * 4);
    int* part0 = (int*)p;           p += aup((size_t)(N1 / 256) * 4);
    int* base0 = (int*)p;           p += aup((size_t)(N1 / 256) * 4);
    int* part1 = (int*)p;           p += aup((size_t)(N2 / 256) * 4);
    int* base1 = (int*)p;           p += aup((size_t)(N2 / 256) * 4);
    int* done  = (int*)p;           p += 256;
    ushort_t* wpk = (ushort_t*)p;   p += aup((size_t)212992 * 2);
    ushort_t* p_pool0  = wpk;                       // 128x128
    ushort_t* p_self0  = p_pool0  + 128 * 128;      // 128x256
    ushort_t* p_neigh0 = p_self0  + 128 * 256;      // 128x256
    ushort_t* p_pool1  = p_neigh0 + 128 * 256;      // 256x256
    ushort_t* p_self1  = p_pool1  + 256 * 256;      // 256x128
    ushort_t* p_neigh1 = p_self1  + 256 * 128;      // 256x128

    PrepArgs pa;
    pa.s0 = PSeg{W_pool0,  p_pool0,  7, 128, 0};
    pa.s1 = PSeg{W_self0,  p_self0,  8, 256, 16384};
    pa.s2 = PSeg{W_neigh0, p_neigh0, 8, 256, 49152};
    pa.s3 = PSeg{W_pool1,  p_pool1,  8, 256, 81920};
    pa.s4 = PSeg{W_self1,  p_self1,  7, 128, 147456};
    pa.s5 = PSeg{W_neigh1, p_neigh1, 7, 128, 180224};
    pa.wtotal = 212992;
    pa.edst0 = edst0; pa.esrc0 = esrc0; pa.E0 = E0;
    pa.edst1 = edst1; pa.esrc1 = esrc1; pa.E1 = E1;
    pa.cnt0 = cnt0; pa.cur0 = cur0; pa.srcs0 = srcs0; pa.dsts0 = dsts0; pa.n0 = N1;
    pa.cnt1 = cnt1; pa.cur1 = cur1; pa.srcs1 = srcs1; pa.dsts1 = dsts1; pa.n1 = N2;
    pa.part0 = part0; pa.base0 = base0;
    pa.part1 = part1; pa.base1 = base1;
    pa.done = done;

    const int EB = (E0 + E1) / 512;           // 880 blocks, 2 edges/thread
    const int SB = (N1 + N2) / 256;           // 176 blocks

    // K1-K4: prep
    prep_pack<<<832, 256, 0, stream>>>(pa);
    prep_count<<<EB, 256, 0, stream>>>(pa);
    prep_scan<<<SB, 256, 0, stream>>>(pa);
    prep_fill<<<EB, 256, 0, stream>>>(pa);

    const uint32 LDS128 = (128 + 8) * 128 * 2;   // 34816
    const uint32 LDS256 = (256 + 8) * 128 * 2;   // 67584

    // D5: agg0 = segmax(relu(h_item[srcs0]@Wpool0 + b))
    pool0_fused<<<E0 / 128, 256, LDS128, stream>>>(
        h_item, p_pool0, b_pool0, srcs0, dsts0, (int*)agg0, E0);

    // D6: h = relu(h_item[:N1]@Wself0 + agg0@Wneigh0 + bias0) -> bf16 [N1,256]
    {
        dim3 g(N1 / 128, (2 * F) / 128);
        gemm_mfma<true, true, false, 128, 128, false, false, 4><<<g, 256, LDS128, stream>>>(
            h_item, p_self0, agg0, p_neigh0, cnt0, bias0, nullptr, (void*)h, 2 * F);
    }

    // D7: agg1 = segmax(relu(h[srcs1]@Wpool1 + b)) -> fp32 [N2,256]
    {
        dim3 g(E1 / 128, 2);
        pool1_fused<<<g, 256, LDS256, stream>>>(
            h, p_pool1, b_pool1, srcs1, dsts1, (int*)agg1, E1);
    }

    // D8: out = h_item_dst + h[:N2]@Wself1 + agg1@Wneigh1 + bias1  [N2,128] fp32
    {
        dim3 g(N2 / 128, F / 128);
        gemm_mfma<false, false, true, 256, 256, true, false, 2><<<g, 256, LDS256, stream>>>(
            h, p_self1, agg1, p_neigh1, cnt1, bias1, h_item_dst, d_out, F);
    }
}

// Round 11
// 189.798 us; speedup vs baseline: 1.0459x; 1.0459x over previous
//
#include <hip/hip_runtime.h>
#include <hip/hip_bf16.h>
#include <cstdint>

// ---------------------------------------------------------------------------
// SAGENet (2-layer SAGEConv 'pool').
// R11 = R9 reverted (best measured: 190.0us). R10's no-agg-zero + staging
// mask + lean grids regressed (+8.5us) -> reverted per post-mortem matrix.
//   K1 pack+zero(cnt+agg); K2 count; K3 chunk-scan; K4 fill
//   D5 pool0_fused: agg0 = segmax(relu(h_item[srcs0]@Wpool0+b))   [R6-verified]
//   D6 gemm3: h = relu(h_item@Wself0 + agg0@Wneigh0 + bias0)      [N1,256] bf16
//   D7 pool1_fused: agg1 = segmax(relu(h[srcs1]@Wpool1+b))        [R7-verified]
//   D8 gemm6: out = h_item_dst + h@Wself1 + agg1@Wneigh1 + bias1  [N2,128]
// Segment-max: dst-sorted edges; interior segments plain stores, block-
// boundary segments int-punned fp32 atomicMax (values >= 0; agg pre-zeroed).
// Shapes fixed: F=128, N1=40960, N2=4096, E0=409600, E1=40960 (%256==0).
// ---------------------------------------------------------------------------

typedef unsigned int uint32;
typedef unsigned short ushort_t;

typedef __attribute__((ext_vector_type(8))) short short8v;   // 8 bf16 (4 VGPR)
typedef __attribute__((ext_vector_type(4))) float float4v;   // MFMA acc

__device__ __forceinline__ float bf_to_f(unsigned short u) {
    union { uint32 u; float f; } cv; cv.u = ((uint32)u) << 16; return cv.f;
}
__device__ __forceinline__ unsigned short f_to_bf(float f) {
    union { float f; uint32 u; } cv; cv.f = f;
    uint32 u = cv.u;
    uint32 r = (u + 0x7FFFu + ((u >> 16) & 1u)) >> 16;  // RNE
    return (unsigned short)r;
}

__device__ __forceinline__ int wave_incl_scan(int v) {
    #pragma unroll
    for (int s = 1; s < 64; s <<= 1) {
        int t = __shfl_up(v, s, 64);
        if ((int)(threadIdx.x & 63) >= s) v += t;
    }
    return v;
}

// ---------------- MFMA GEMM ------------------------------------------------
template<int KT, bool ABF>
__device__ __forceinline__ void gemm_seg(
    const void* __restrict__ Av, const ushort_t* __restrict__ Wp, int N,
    int row0, int col0, int tid, int wr, int wc, int l15, int g,
    ushort_t* lds, float4v (&acc)[4][4])
{
    constexpr int ldl = KT + 8;
    __syncthreads();
    if constexpr (ABF) {
        const ushort_t* A = (const ushort_t*)Av;
        constexpr int C8 = KT / 8;
        constexpr int TOT = 128 * C8;
        #pragma unroll 4
        for (int L = tid; L < TOT; L += 256) {
            int row = L / C8;
            int c8  = (L % C8) * 8;
            *(uint4*)&lds[row * ldl + c8] =
                *(const uint4*)(A + (size_t)(row0 + row) * KT + c8);
        }
    } else {
        const float* A = (const float*)Av;
        constexpr int C4 = KT / 4;
        constexpr int TOT = 128 * C4;
        #pragma unroll 4
        for (int L = tid; L < TOT; L += 256) {
            int row = L / C4;
            int c4  = (L % C4) * 4;
            float4 v = *(const float4*)(A + (size_t)(row0 + row) * KT + c4);
            ushort4 pk = make_ushort4(f_to_bf(v.x), f_to_bf(v.y), f_to_bf(v.z), f_to_bf(v.w));
            *(ushort4*)&lds[row * ldl + c4] = pk;
        }
    }
    __syncthreads();

    #pragma unroll
    for (int s = 0; s < KT / 32; ++s) {
        const int kb = s * 4 + g;
        short8v bfr[4], afr[4];
        #pragma unroll
        for (int ni = 0; ni < 4; ++ni) {
            int col = col0 + wc * 64 + ni * 16 + l15;
            bfr[ni] = *(const short8v*)(Wp + ((size_t)kb * N + col) * 8);
        }
        #pragma unroll
        for (int mi = 0; mi < 4; ++mi) {
            int row = wr * 64 + mi * 16 + l15;
            afr[mi] = *(const short8v*)&lds[row * ldl + s * 32 + g * 8];
        }
        #pragma unroll
        for (int mi = 0; mi < 4; ++mi)
            #pragma unroll
            for (int ni = 0; ni < 4; ++ni)
                acc[mi][ni] = __builtin_amdgcn_mfma_f32_16x16x32_bf16(
                    afr[mi], bfr[ni], acc[mi][ni], 0, 0, 0);
    }
}

template<bool RELU, bool BF16_OUT, bool HAS_ADD, int K0T, int K1T, bool A0BF, bool A1BF, int MINW>
__global__ __launch_bounds__(256, MINW) void gemm_mfma(
    const void* __restrict__ A0, const ushort_t* __restrict__ Wp0,
    const void* __restrict__ A1, const ushort_t* __restrict__ Wp1,
    const float* __restrict__ bias, const float* __restrict__ addsrc,
    void* __restrict__ Cout, int N)
{
    extern __shared__ ushort_t lds[];
    const int tid  = threadIdx.x;
    const int lane = tid & 63;
    const int wid  = tid >> 6;
    const int wr = wid >> 1, wc = wid & 1;
    const int row0 = blockIdx.x * 128;
    const int col0 = blockIdx.y * 128;
    const int l15 = lane & 15, g = lane >> 4;

    float4v acc[4][4];
    #pragma unroll
    for (int i = 0; i < 4; ++i)
        #pragma unroll
        for (int j = 0; j < 4; ++j)
            acc[i][j] = (float4v){0.f, 0.f, 0.f, 0.f};

    gemm_seg<K0T, A0BF>(A0, Wp0, N, row0, col0, tid, wr, wc, l15, g, lds, acc);
    if constexpr (K1T > 0)
        gemm_seg<K1T, A1BF>(A1, Wp1, N, row0, col0, tid, wr, wc, l15, g, lds, acc);

    // epilogue: C/D layout col=lane&15, row=(lane>>4)*4+reg  [m89-verified]
    if constexpr (BF16_OUT) {
        __syncthreads();
        #pragma unroll
        for (int mi = 0; mi < 4; ++mi) {
            #pragma unroll
            for (int ni = 0; ni < 4; ++ni) {
                const int rowl = wr * 64 + mi * 16 + g * 4;
                const int coll = wc * 64 + ni * 16 + l15;
                const float bs = bias[col0 + coll];
                #pragma unroll
                for (int q = 0; q < 4; ++q) {
                    float v = acc[mi][ni][q] + bs;
                    if (RELU) v = fmaxf(v, 0.f);
                    lds[(rowl + q) * 136 + coll] = f_to_bf(v);
                }
            }
        }
        __syncthreads();
        ushort_t* Cb = (ushort_t*)Cout;
        const int rloc = tid >> 4, c8 = (tid & 15) * 8;
        #pragma unroll
        for (int p = 0; p < 8; ++p) {
            int r = p * 16 + rloc;
            uint4 v = *(const uint4*)&lds[r * 136 + c8];
            *(uint4*)&Cb[(size_t)(row0 + r) * N + col0 + c8] = v;
        }
    } else {
        float* C = (float*)Cout;
        #pragma unroll
        for (int mi = 0; mi < 4; ++mi) {
            #pragma unroll
            for (int ni = 0; ni < 4; ++ni) {
                const int rowb = row0 + wr * 64 + mi * 16 + g * 4;
                const int col  = col0 + wc * 64 + ni * 16 + l15;
                const float bs = bias[col];
                #pragma unroll
                for (int q = 0; q < 4; ++q) {
                    float v = acc[mi][ni][q] + bs;
                    if (HAS_ADD) v += addsrc[(size_t)(rowb + q) * N + col];
                    if (RELU) v = fmaxf(v, 0.f);
                    C[(size_t)(rowb + q) * N + col] = v;
                }
            }
        }
    }
}

// ---------------- fused pool GEMM + segment-max ----------------------------
__global__ __launch_bounds__(256, 4) void pool0_fused(
    const float* __restrict__ hsrc, const ushort_t* __restrict__ Wp,
    const float* __restrict__ bias,
    const int* __restrict__ srcs, const int* __restrict__ dsts,
    int* __restrict__ agg, int E)
{
    constexpr int KT = 128, ldl = KT + 8;      // 136
    extern __shared__ ushort_t lds[];
    __shared__ int sIdx[128], sd[128];
    __shared__ int segbeg[129];
    __shared__ int wps[4];
    __shared__ int s_first_start, s_last_end;

    const int tid  = threadIdx.x;
    const int lane = tid & 63;
    const int wid  = tid >> 6;
    const int wr = wid >> 1, wc = wid & 1;
    const int l15 = lane & 15, g = lane >> 4;
    const int r0 = blockIdx.x * 128;

    if (tid < 128) { sIdx[tid] = srcs[r0 + tid]; sd[tid] = dsts[r0 + tid]; }
    __syncthreads();

    #pragma unroll 4
    for (int L = tid; L < 128 * 32; L += 256) {
        int row = L >> 5;
        int c4  = (L & 31) * 4;
        float4 v = *(const float4*)(hsrc + (size_t)sIdx[row] * KT + c4);
        ushort4 pk = make_ushort4(f_to_bf(v.x), f_to_bf(v.y), f_to_bf(v.z), f_to_bf(v.w));
        *(ushort4*)&lds[row * ldl + c4] = pk;
    }
    __syncthreads();

    float4v acc[4][4];
    #pragma unroll
    for (int i = 0; i < 4; ++i)
        #pragma unroll
        for (int j = 0; j < 4; ++j)
            acc[i][j] = (float4v){0.f, 0.f, 0.f, 0.f};

    #pragma unroll
    for (int s = 0; s < KT / 32; ++s) {
        const int kb = s * 4 + g;
        short8v bfr[4], afr[4];
        #pragma unroll
        for (int ni = 0; ni < 4; ++ni) {
            int col = wc * 64 + ni * 16 + l15;
            bfr[ni] = *(const short8v*)(Wp + ((size_t)kb * 128 + col) * 8);
        }
        #pragma unroll
        for (int mi = 0; mi < 4; ++mi) {
            int row = wr * 64 + mi * 16 + l15;
            afr[mi] = *(const short8v*)&lds[row * ldl + s * 32 + g * 8];
        }
        #pragma unroll
        for (int mi = 0; mi < 4; ++mi)
            #pragma unroll
            for (int ni = 0; ni < 4; ++ni)
                acc[mi][ni] = __builtin_amdgcn_mfma_f32_16x16x32_bf16(
                    afr[mi], bfr[ni], acc[mi][ni], 0, 0, 0);
    }

    __syncthreads();
    #pragma unroll
    for (int mi = 0; mi < 4; ++mi) {
        #pragma unroll
        for (int ni = 0; ni < 4; ++ni) {
            const int rowl = wr * 64 + mi * 16 + g * 4;
            const int coll = wc * 64 + ni * 16 + l15;
            const float bs = bias[coll];
            #pragma unroll
            for (int q = 0; q < 4; ++q) {
                float v = fmaxf(acc[mi][ni][q] + bs, 0.f);
                lds[(rowl + q) * ldl + coll] = f_to_bf(v);
            }
        }
    }

    int flag = 0;
    if (tid < 128) flag = (tid == 0) || (sd[tid] != sd[tid - 1]);
    int isc = wave_incl_scan(flag);
    if (lane == 63) wps[wid] = isc;
    if (tid == 0) {
        s_first_start = (r0 == 0) || (dsts[r0 - 1] != sd[0]);
        s_last_end    = (r0 + 128 == E) || (dsts[r0 + 128] != sd[127]);
    }
    __syncthreads();
    int woff = (wid >= 1) ? wps[0] : 0;
    if (tid < 128 && flag) segbeg[woff + isc - 1] = tid;
    __syncthreads();
    const int nseg = wps[0] + wps[1];
    const bool first_start = s_first_start, last_end = s_last_end;

    for (int it = tid; it < nseg * 64; it += 256) {
        int s  = it >> 6;
        int cp = it & 63;
        int beg = segbeg[s];
        int end = (s + 1 < nseg) ? segbeg[s + 1] : 128;
        int d = sd[beg];
        uint32 mx0 = 0, mx1 = 0;
        for (int r = beg; r < end; ++r) {
            ushort2 v = *(const ushort2*)&lds[r * ldl + cp * 2];
            if (v.x > mx0) mx0 = v.x;
            if (v.y > mx1) mx1 = v.y;
        }
        float f0 = bf_to_f((ushort_t)mx0), f1 = bf_to_f((ushort_t)mx1);
        int* p = agg + (size_t)d * 128 + cp * 2;
        bool interior = (s > 0 || first_start) && (s < nseg - 1 || last_end);
        if (interior) {
            *(float2*)p = make_float2(f0, f1);
        } else {
            atomicMax(p,     __float_as_int(f0));
            atomicMax(p + 1, __float_as_int(f1));
        }
    }
}

// layer-1 variant: K=256, A gathered from bf16 h; 128-col half per blockIdx.y.
__global__ __launch_bounds__(256, 2) void pool1_fused(
    const ushort_t* __restrict__ hsrc,      // bf16 [N1,256]
    const ushort_t* __restrict__ Wp,        // packed [256/8][256][8]
    const float* __restrict__ bias,         // [256]
    const int* __restrict__ srcs, const int* __restrict__ dsts,
    int* __restrict__ agg, int E)           // fp32 [N2,256]
{
    constexpr int KT = 256, ldl = KT + 8;   // 264
    constexpr int ldt = 136;
    extern __shared__ ushort_t lds[];
    __shared__ int sIdx[128], sd[128];
    __shared__ int segbeg[129];
    __shared__ int wps[4];
    __shared__ int s_first_start, s_last_end;

    const int tid  = threadIdx.x;
    const int lane = tid & 63;
    const int wid  = tid >> 6;
    const int wr = wid >> 1, wc = wid & 1;
    const int l15 = lane & 15, g = lane >> 4;
    const int r0 = blockIdx.x * 128;
    const int col0 = blockIdx.y * 128;

    if (tid < 128) { sIdx[tid] = srcs[r0 + tid]; sd[tid] = dsts[r0 + tid]; }
    __syncthreads();

    #pragma unroll 4
    for (int L = tid; L < 128 * 32; L += 256) {
        int row = L >> 5;
        int c8  = (L & 31) * 8;
        *(uint4*)&lds[row * ldl + c8] =
            *(const uint4*)(hsrc + (size_t)sIdx[row] * KT + c8);
    }
    __syncthreads();

    float4v acc[4][4];
    #pragma unroll
    for (int i = 0; i < 4; ++i)
        #pragma unroll
        for (int j = 0; j < 4; ++j)
            acc[i][j] = (float4v){0.f, 0.f, 0.f, 0.f};

    #pragma unroll
    for (int s = 0; s < KT / 32; ++s) {
        const int kb = s * 4 + g;
        short8v bfr[4], afr[4];
        #pragma unroll
        for (int ni = 0; ni < 4; ++ni) {
            int col = col0 + wc * 64 + ni * 16 + l15;
            bfr[ni] = *(const short8v*)(Wp + ((size_t)kb * 256 + col) * 8);
        }
        #pragma unroll
        for (int mi = 0; mi < 4; ++mi) {
            int row = wr * 64 + mi * 16 + l15;
            afr[mi] = *(const short8v*)&lds[row * ldl + s * 32 + g * 8];
        }
        #pragma unroll
        for (int mi = 0; mi < 4; ++mi)
            #pragma unroll
            for (int ni = 0; ni < 4; ++ni)
                acc[mi][ni] = __builtin_amdgcn_mfma_f32_16x16x32_bf16(
                    afr[mi], bfr[ni], acc[mi][ni], 0, 0, 0);
    }

    __syncthreads();
    #pragma unroll
    for (int mi = 0; mi < 4; ++mi) {
        #pragma unroll
        for (int ni = 0; ni < 4; ++ni) {
            const int rowl = wr * 64 + mi * 16 + g * 4;
            const int coll = wc * 64 + ni * 16 + l15;
            const float bs = bias[col0 + coll];
            #pragma unroll
            for (int q = 0; q < 4; ++q) {
                float v = fmaxf(acc[mi][ni][q] + bs, 0.f);
                lds[(rowl + q) * ldt + coll] = f_to_bf(v);
            }
        }
    }

    int flag = 0;
    if (tid < 128) flag = (tid == 0) || (sd[tid] != sd[tid - 1]);
    int isc = wave_incl_scan(flag);
    if (lane == 63) wps[wid] = isc;
    if (tid == 0) {
        s_first_start = (r0 == 0) || (dsts[r0 - 1] != sd[0]);
        s_last_end    = (r0 + 128 == E) || (dsts[r0 + 128] != sd[127]);
    }
    __syncthreads();
    int woff = (wid >= 1) ? wps[0] : 0;
    if (tid < 128 && flag) segbeg[woff + isc - 1] = tid;
    __syncthreads();
    const int nseg = wps[0] + wps[1];
    const bool first_start = s_first_start, last_end = s_last_end;

    for (int it = tid; it < nseg * 64; it += 256) {
        int s  = it >> 6;
        int cp = it & 63;
        int beg = segbeg[s];
        int end = (s + 1 < nseg) ? segbeg[s + 1] : 128;
        int d = sd[beg];
        uint32 mx0 = 0, mx1 = 0;
        for (int r = beg; r < end; ++r) {
            ushort2 v = *(const ushort2*)&lds[r * ldt + cp * 2];
            if (v.x > mx0) mx0 = v.x;
            if (v.y > mx1) mx1 = v.y;
        }
        float f0 = bf_to_f((ushort_t)mx0), f1 = bf_to_f((ushort_t)mx1);
        int* p = agg + (size_t)d * 256 + col0 + cp * 2;
        bool interior = (s > 0 || first_start) && (s < nseg - 1 || last_end);
        if (interior) {
            *(float2*)p = make_float2(f0, f1);
        } else {
            atomicMax(p,     __float_as_int(f0));
            atomicMax(p + 1, __float_as_int(f1));
        }
    }
}

// ---------------- prep kernels ---------------------------------------------
struct PSeg { const float* src; ushort_t* dst; int lgN; int N; int base; };

struct PrepArgs {
    PSeg s0, s1, s2, s3, s4, s5; int wtotal;
    const int *edst0, *esrc0; int E0;
    const int *edst1, *esrc1; int E1;
    int *cnt0, *cur0, *srcs0, *dsts0; int n0;
    int *cnt1, *cur1, *srcs1, *dsts1; int n1;
    int *part0, *base0;                 // [n0/256]
    int *part1, *base1;                 // [n1/256]
    float4 *agg0z; int nz0;
    float4 *agg1z; int nz1;
    int *done;
};

__device__ __forceinline__ void pack_one(const PrepArgs& a, int idx)
{
    PSeg s;
    if      (idx >= a.s5.base) s = a.s5;
    else if (idx >= a.s4.base) s = a.s4;
    else if (idx >= a.s3.base) s = a.s3;
    else if (idx >= a.s2.base) s = a.s2;
    else if (idx >= a.s1.base) s = a.s1;
    else                       s = a.s0;
    int e = idx - s.base;
    int k = e >> s.lgN;
    int n = e & (s.N - 1);
    s.dst[((size_t)(k >> 3) * s.N + n) * 8 + (k & 7)] = f_to_bf(s.src[e]);
}

// K1: pack weights + zero counters/aggs/done.
__global__ __launch_bounds__(256) void prep_pack(PrepArgs a)
{
    const int gid = blockIdx.x * 256 + threadIdx.x;
    const int nth = gridDim.x * 256;
    const float4 z4 = make_float4(0.f, 0.f, 0.f, 0.f);
    if (gid == 0) *a.done = 0;
    for (int i = gid; i < a.n0; i += nth) a.cnt0[i] = 0;
    for (int i = gid; i < a.n1; i += nth) a.cnt1[i] = 0;
    for (int i = gid; i < a.nz0; i += nth) a.agg0z[i] = z4;
    for (int i = gid; i < a.nz1; i += nth) a.agg1z[i] = z4;
    for (int i = gid; i < a.wtotal; i += nth) pack_one(a, i);
}

// K2: count (1 edge/thread, both layers).
__global__ __launch_bounds__(256) void prep_count(PrepArgs a)
{
    const int e = blockIdx.x * 256 + threadIdx.x;
    if (e < a.E0) atomicAdd(&a.cnt0[a.edst0[e]], 1);
    const int e1 = e - a.E0;
    if (e1 >= 0 && e1 < a.E1) atomicAdd(&a.cnt1[a.edst1[e1]], 1);
}

// K3: per-256-chunk exclusive scan -> cur (within-chunk offsets) + partial.
// Last-finishing block scans the 176 partials -> base arrays.
__global__ __launch_bounds__(256) void prep_scan(PrepArgs a)
{
    __shared__ int wsum[4];
    __shared__ int s_last;
    const int tid = threadIdx.x;
    const int lane = tid & 63, wid = tid >> 6;
    const int nchunk0 = a.n0 >> 8;          // 160
    const int nchunk1 = a.n1 >> 8;          // 16
    const int c = blockIdx.x;
    const bool is0 = (c < nchunk0);
    const int cc = is0 ? c : (c - nchunk0);
    int* cnt  = is0 ? a.cnt0  : a.cnt1;
    int* cur  = is0 ? a.cur0  : a.cur1;
    int* part = is0 ? a.part0 : a.part1;
    const int base = cc * 256;

    int v = cnt[base + tid];
    int is = wave_incl_scan(v);
    if (lane == 63) wsum[wid] = is;
    __syncthreads();
    if (tid == 0) {
        int acc = 0;
        #pragma unroll
        for (int j = 0; j < 4; ++j) { int t = wsum[j]; wsum[j] = acc; acc += t; }
    }
    __syncthreads();
    cur[base + tid] = wsum[wid] + is - v;
    if (tid == 255) part[cc] = wsum[3] + is;   // chunk total

    __syncthreads();
    if (tid == 0) {
        __threadfence();
        s_last = (atomicAdd(a.done, 1) == (int)gridDim.x - 1);
    }
    __syncthreads();
    if (s_last) {
        __threadfence();
        int p0 = (tid < nchunk0) ? a.part0[tid] : 0;
        int isc = wave_incl_scan(p0);
        __syncthreads();
        if (lane == 63) wsum[wid] = isc;
        __syncthreads();
        if (tid == 0) {
            int acc = 0;
            #pragma unroll
            for (int j = 0; j < 4; ++j) { int t = wsum[j]; wsum[j] = acc; acc += t; }
        }
        __syncthreads();
        if (tid < nchunk0) a.base0[tid] = wsum[wid] + isc - p0;
        if (tid == 0) {
            int acc = 0;
            for (int j = 0; j < nchunk1; ++j) { a.base1[j] = acc; acc += a.part1[j]; }
        }
    }
}

// K4: fill dst-sorted srcs/dsts: pos = base[d>>8] + atomicAdd(cur[d]).
__global__ __launch_bounds__(256) void prep_fill(PrepArgs a)
{
    const int e = blockIdx.x * 256 + threadIdx.x;
    if (e < a.E0) {
        int d = a.edst0[e];
        int p = a.base0[d >> 8] + atomicAdd(&a.cur0[d], 1);
        a.srcs0[p] = a.esrc0[e];
        a.dsts0[p] = d;
    }
    const int e1 = e - a.E0;
    if (e1 >= 0 && e1 < a.E1) {
        int d = a.edst1[e1];
        int p = a.base1[d >> 8] + atomicAdd(&a.cur1[d], 1);
        a.srcs1[p] = a.esrc1[e1];
        a.dsts1[p] = d;
    }
}

// ---------------------------------------------------------------------------

extern "C" void kernel_launch(void* const* d_in, const int* in_sizes, int n_in,
                              void* d_out, int out_size, void* d_ws, size_t ws_size,
                              hipStream_t stream)
{
    const float* h_item     = (const float*)d_in[0];
    const float* h_item_dst = (const float*)d_in[1];
    const int*   esrc0      = (const int*)d_in[2];
    const int*   edst0      = (const int*)d_in[3];
    const int*   esrc1      = (const int*)d_in[4];
    const int*   edst1      = (const int*)d_in[5];
    const float* W_pool0  = (const float*)d_in[7];
    const float* b_pool0  = (const float*)d_in[8];
    const float* W_self0  = (const float*)d_in[9];
    const float* W_neigh0 = (const float*)d_in[10];
    const float* bias0    = (const float*)d_in[11];
    const float* W_pool1  = (const float*)d_in[12];
    const float* b_pool1  = (const float*)d_in[13];
    const float* W_self1  = (const float*)d_in[14];
    const float* W_neigh1 = (const float*)d_in[15];
    const float* bias1    = (const float*)d_in[16];

    const int F  = 128;
    const int N2 = in_sizes[1] / F;     // 4096
    const int E0 = in_sizes[2];         // 409600 (%128==0)
    const int E1 = in_sizes[4];         // 40960  (%128==0)
    const int N1 = 40960;               // num_mid (fixed)

    auto aup = [](size_t x) { return (x + 255) & ~(size_t)255; };
    char* p = (char*)d_ws;

    float* agg0 = (float*)p;        p += aup((size_t)N1 * F * 4);        // fp32 [N1,128]
    ushort_t* h = (ushort_t*)p;     p += aup((size_t)N1 * 2 * F * 2);    // bf16 [N1,256]
    float* agg1 = (float*)p;        p += aup((size_t)N2 * 2 * F * 4);    // fp32 [N2,256]
    int* cnt0  = (int*)p;           p += aup((size_t)N1 * 4);
    int* cur0  = (int*)p;           p += aup((size_t)N1 * 4);
    int* srcs0 = (int*)p;           p += aup((size_t)E0 * 4);
    int* dsts0 = (int*)p;           p += aup((size_t)E0 * 4);
    int* cnt1  = (int*)p;           p += aup((size_t)N2 * 4);
    int* cur1  = (int*)p;           p += aup((size_t)N2 * 4);
    int* srcs1 = (int*)p;           p += aup((size_t)E1 * 4);
    int* dsts1 = (int*)p;           p += aup((size_t)E1 * 4);
    int* part0 = (int*)p;           p += aup((size_t)(N1 / 256) * 4);
    int* base0 = (int*)p;           p += aup((size_t)(N1 / 256) * 4);
    int* part1 = (int*)p;           p += aup((size_t)(N2 / 256) * 4);
    int* base1 = (int*)p;           p += aup((size_t)(N2 / 256) * 4);
    int* done  = (int*)p;           p += 256;
    ushort_t* wpk = (ushort_t*)p;   p += aup((size_t)212992 * 2);
    ushort_t* p_pool0  = wpk;                       // 128x128
    ushort_t* p_self0  = p_pool0  + 128 * 128;      // 128x256
    ushort_t* p_neigh0 = p_self0  + 128 * 256;      // 128x256
    ushort_t* p_pool1  = p_neigh0 + 128 * 256;      // 256x256
    ushort_t* p_self1  = p_pool1  + 256 * 256;      // 256x128
    ushort_t* p_neigh1 = p_self1  + 256 * 128;      // 256x128

    PrepArgs pa;
    pa.s0 = PSeg{W_pool0,  p_pool0,  7, 128, 0};
    pa.s1 = PSeg{W_self0,  p_self0,  8, 256, 16384};
    pa.s2 = PSeg{W_neigh0, p_neigh0, 8, 256, 49152};
    pa.s3 = PSeg{W_pool1,  p_pool1,  8, 256, 81920};
    pa.s4 = PSeg{W_self1,  p_self1,  7, 128, 147456};
    pa.s5 = PSeg{W_neigh1, p_neigh1, 7, 128, 180224};
    pa.wtotal = 212992;
    pa.edst0 = edst0; pa.esrc0 = esrc0; pa.E0 = E0;
    pa.edst1 = edst1; pa.esrc1 = esrc1; pa.E1 = E1;
    pa.cnt0 = cnt0; pa.cur0 = cur0; pa.srcs0 = srcs0; pa.dsts0 = dsts0; pa.n0 = N1;
    pa.cnt1 = cnt1; pa.cur1 = cur1; pa.srcs1 = srcs1; pa.dsts1 = dsts1; pa.n1 = N2;
    pa.part0 = part0; pa.base0 = base0;
    pa.part1 = part1; pa.base1 = base1;
    pa.agg0z = (float4*)agg0; pa.nz0 = N1 * F / 4;
    pa.agg1z = (float4*)agg1; pa.nz1 = N2 * 2 * F / 4;
    pa.done = done;

    const int EB = (E0 + E1) / 256;           // 1760 blocks
    const int SB = (N1 + N2) / 256;           // 176 blocks

    // K1-K4: prep
    prep_pack<<<1024, 256, 0, stream>>>(pa);
    prep_count<<<EB, 256, 0, stream>>>(pa);
    prep_scan<<<SB, 256, 0, stream>>>(pa);
    prep_fill<<<EB, 256, 0, stream>>>(pa);

    const uint32 LDS128 = (128 + 8) * 128 * 2;   // 34816
    const uint32 LDS256 = (256 + 8) * 128 * 2;   // 67584

    // D5: agg0 = segmax(relu(h_item[srcs0]@Wpool0 + b))
    pool0_fused<<<E0 / 128, 256, LDS128, stream>>>(
        h_item, p_pool0, b_pool0, srcs0, dsts0, (int*)agg0, E0);

    // D6: h = relu(h_item[:N1]@Wself0 + agg0@Wneigh0 + bias0) -> bf16 [N1,256]
    {
        dim3 g(N1 / 128, (2 * F) / 128);
        gemm_mfma<true, true, false, 128, 128, false, false, 4><<<g, 256, LDS128, stream>>>(
            h_item, p_self0, agg0, p_neigh0, bias0, nullptr, (void*)h, 2 * F);
    }

    // D7: agg1 = segmax(relu(h[srcs1]@Wpool1 + b)) -> fp32 [N2,256]
    {
        dim3 g(E1 / 128, 2);
        pool1_fused<<<g, 256, LDS256, stream>>>(
            h, p_pool1, b_pool1, srcs1, dsts1, (int*)agg1, E1);
    }

    // D8: out = h_item_dst + h[:N2]@Wself1 + agg1@Wneigh1 + bias1  [N2,128] fp32
    {
        dim3 g(N2 / 128, F / 128);
        gemm_mfma<false, false, true, 256, 256, true, false, 2><<<g, 256, LDS256, stream>>>(
            h, p_self1, agg1, p_neigh1, bias1, h_item_dst, d_out, F);
    }
}